// Round 13
// baseline (2328.664 us; speedup 1.0000x reference)
//
#include <hip/hip_runtime.h>
#include <math.h>
#include <stdint.h>

// Keep compiler contraction OFF globally: the ONLY fusions are my explicit
// fmaf() calls, which model LLVM's contract-FMF fusion on the XLA CPU host.
#pragma clang fp contract(off)

#define N_PIX 802816          // 16*1*224*224 = 512*1568
#define T_WIN 100
#define KN_MAX 96             // Knuth subkey chain length
#define RJ_MAX 48             // rejection subkey chain length (G ~ 10)
#define N_CHUNKS (N_PIX / 64) // 12544 wave-chunks

#define G_SLOT 384            // = KN_MAX*2 + RJ_MAX*4
#define MRC_WS  385           // 8 floats: make_rej(1e5) fields
#define CTR0_WS 393           // pass0 work-steal counter
#define CTR1_WS 394           // pass1 work-steal counter
#define TAB_WS  395
#define TAB_BASE 98000
#define TAB_N    4096
#define BM_WS   4492          // per-pixel 2xu64 bitmap; 4492*4 % 16 == 0
#define WS_TAB_NEEDED ((size_t)(TAB_WS + TAB_N) * 4)
#define WS_FAST_NEEDED ((size_t)(BM_WS + 4 * N_PIX) * 4)   // ~12.9 MB

// ---------------- threefry2x32 (JAX rotation/injection schedule) -------------
__device__ __forceinline__ void tf2x32(uint32_t k0, uint32_t k1,
                                       uint32_t x0, uint32_t x1,
                                       uint32_t &o0, uint32_t &o1) {
  uint32_t ks2 = k0 ^ k1 ^ 0x1BD11BDAu;
  x0 += k0; x1 += k1;
#define TF_R(r) { x0 += x1; x1 = (x1 << (r)) | (x1 >> (32 - (r))); x1 ^= x0; }
  TF_R(13) TF_R(15) TF_R(26) TF_R(6)
  x0 += k1;  x1 += ks2 + 1u;
  TF_R(17) TF_R(29) TF_R(16) TF_R(24)
  x0 += ks2; x1 += k0 + 2u;
  TF_R(13) TF_R(15) TF_R(26) TF_R(6)
  x0 += k0;  x1 += k1 + 3u;
  TF_R(17) TF_R(29) TF_R(16) TF_R(24)
  x0 += k1;  x1 += ks2 + 4u;
  TF_R(13) TF_R(15) TF_R(26) TF_R(6)
  x0 += ks2; x1 += k0 + 5u;
#undef TF_R
  o0 = x0; o1 = x1;
}

__device__ __forceinline__ uint32_t unif_bits(uint32_t s0, uint32_t s1, uint32_t p) {
  uint32_t a, b;
  tf2x32(s0, s1, 0u, p, a, b);
  return a ^ b;
}

__device__ __forceinline__ float bits_to_unit(uint32_t bits) {
  return __uint_as_float(0x3f800000u | (bits >> 9)) - 1.0f;
}

// ---------------- XLA CPU f32 log (verified bit-exact in round 5) ------------
__device__ __forceinline__ float xla_logf(float xin) {
#pragma clang fp contract(off)
  if (xin == 0.0f) return __uint_as_float(0xff800000u);           // -inf
  if (!(xin > 0.0f)) return __uint_as_float(0x7fc00000u);         // nan
  float x = fmaxf(xin, __uint_as_float(0x00800000u));             // flush denorm
  uint32_t ib = __float_as_uint(x);
  float e = (float)((int)(ib >> 23) - 126);
  ib = (ib & 0x007fffffu) | 0x3f000000u;                          // [0.5,1)
  x = __uint_as_float(ib);
  float tmp = 0.0f, eadj = 0.0f;
  if (x < (float)0.707106781186547524) { tmp = x; eadj = 1.0f; }
  x = x - 1.0f;
  e = e - eadj;
  x = x + tmp;
  float x2 = x * x;
  float x3 = x2 * x;
  float y  = fmaf((float)7.0376836292e-2,  x, (float)-1.1514610310e-1);
  float y1 = fmaf((float)-1.2420140846e-1, x, (float)1.4249322787e-1);
  float y2 = fmaf((float)2.0000714765e-1,  x, (float)-2.4999993993e-1);
  y  = fmaf(y,  x, (float)1.1676998740e-1);
  y1 = fmaf(y1, x, (float)-1.6668057665e-1);
  y2 = fmaf(y2, x, (float)3.3333331174e-1);
  y  = fmaf(y, x3, y1);
  y  = fmaf(y, x3, y2);
  float eq1 = e * (float)-2.12194440e-4;   // standalone mul
  y = fmaf(y, x3, eq1);                    // fadd(mul,mul): operand-0 fuses
  x = fmaf(-x2, 0.5f, x);                  // fsub(x, mul) -> fnmadd
  x = x + y;                               // add of two fma results
  x = fmaf(e, (float)0.693359375, x);      // fadd(x, mul) -> fma
  return x;
}

__device__ __forceinline__ float xla_log1pf(float w) {
#pragma clang fp contract(off)
  if (fabsf(w) < (float)1e-4) return fmaf(-0.5f, w, 1.0f) * w;
  return xla_logf(w + 1.0f);
}

__device__ __forceinline__ float xla_lgammaf_pos(float x) {
#pragma clang fp contract(off)
  const float kBase = (float)0.99999999999980993227684700473478;
  const float c0 = (float)676.520368121885098567009190444019;
  const float c1 = (float)-1259.13921672240287047156078755283;
  const float c2 = (float)771.3234287776530788486528258894;
  const float c3 = (float)-176.61502916214059906584551354;
  const float c4 = (float)12.507343278686904814458936853;
  const float c5 = (float)-0.13857109526572011689554707;
  const float c6 = (float)9.984369578019570859563e-6;
  const float c7 = (float)1.50563273514931155834e-7;
  const float kLogSqrtTwoPi = (float)0.91893853320467274178032973640562;
  const float kGPlusHalf = 7.5f;
  const float kLogGPlusHalf = (float)2.0149030205422647065; // log(7.5)
  float z = x - 1.0f;
  float sum = kBase;
  sum = sum + c0 / ((z + 0.0f) + 1.0f);
  sum = sum + c1 / ((z + 1.0f) + 1.0f);
  sum = sum + c2 / ((z + 2.0f) + 1.0f);
  sum = sum + c3 / ((z + 3.0f) + 1.0f);
  sum = sum + c4 / ((z + 4.0f) + 1.0f);
  sum = sum + c5 / ((z + 5.0f) + 1.0f);
  sum = sum + c6 / ((z + 6.0f) + 1.0f);
  sum = sum + c7 / ((z + 7.0f) + 1.0f);
  float t = kGPlusHalf + z;
  float log_t = kLogGPlusHalf + xla_log1pf(z / kGPlusHalf);
  float log_y = fmaf((z + 0.5f) - t / log_t, log_t, kLogSqrtTwoPi) + xla_logf(sum);
  return log_y;
}

// ---------------- rejection sampler shared pieces ----------------------------
struct RejConst {
  float lam, neg_lam, log_lam, aa, bb, inv_alpha, v_r, two_a;
};

__device__ __forceinline__ RejConst make_rej(float lam) {
  RejConst rc;
  rc.lam = lam;
  rc.neg_lam = -lam;
  rc.log_lam = xla_logf(lam);
  float sq = (float)sqrt((double)lam);                  // CR f32 sqrt
  rc.bb = fmaf(2.53f, sq, (float)0.931);
  rc.aa = fmaf((float)0.02483, rc.bb, (float)-0.059);
  rc.inv_alpha = (float)1.1239 + (float)1.1328 / (rc.bb - (float)3.4);
  rc.v_r = (float)0.9277 - (float)3.6224 / (rc.bb - 2.0f);
  rc.two_a = 2.0f * rc.aa;
  return rc;
}

// v_r only (for pass0 accept1) -- EXACT same op sequence as make_rej's v_r.
__device__ __forceinline__ float vr_only(float lam) {
  float sq = (float)sqrt((double)lam);
  float bb = fmaf(2.53f, sq, (float)0.931);
  return (float)0.9277 - (float)3.6224 / (bb - 2.0f);
}

// One rejection iteration (full lgamma) -- byte-identical to rounds 5-12.
__device__ __forceinline__ bool rej_step4(const RejConst& rc, uint4 ch,
                                          uint32_t p, float& kf_out) {
  float u = bits_to_unit(unif_bits(ch.x, ch.y, p)) - 0.5f;
  float v = bits_to_unit(unif_bits(ch.z, ch.w, p));
  float u_sh = 0.5f - fabsf(u);
  float kf = floorf(fmaf(rc.two_a / u_sh + rc.bb, u, rc.lam) + (float)0.43);
  kf_out = kf;
  if ((u_sh >= (float)0.07) && (v <= rc.v_r)) return true;          // accept1
  if ((kf < 0.0f) || ((u_sh < (float)0.013) && (v > u_sh))) return false; // reject
  float sv = xla_logf((v * rc.inv_alpha) / ((rc.aa / (u_sh * u_sh)) + rc.bb));
  float tv = fmaf(kf, rc.log_lam, rc.neg_lam) - xla_lgammaf_pos(kf + 1.0f);
  return sv <= tv;                                                  // accept2
}

// Table-assisted via GLOBAL table read (L2); identical bits (table = fn(kf)).
__device__ __forceinline__ bool rej_step_tab_g(const RejConst& rc, uint4 ch,
                                               uint32_t p,
                                               const uint32_t* __restrict__ ws,
                                               float& kf_out) {
  float u = bits_to_unit(unif_bits(ch.x, ch.y, p)) - 0.5f;
  float v = bits_to_unit(unif_bits(ch.z, ch.w, p));
  float u_sh = 0.5f - fabsf(u);
  float kf = floorf(fmaf(rc.two_a / u_sh + rc.bb, u, rc.lam) + (float)0.43);
  kf_out = kf;
  if ((u_sh >= (float)0.07) && (v <= rc.v_r)) return true;          // accept1
  if ((kf < 0.0f) || ((u_sh < (float)0.013) && (v > u_sh))) return false; // reject
  float sv = xla_logf((v * rc.inv_alpha) / ((rc.aa / (u_sh * u_sh)) + rc.bb));
  int ki = (int)kf - TAB_BASE;
  float lg = (ki >= 0 && ki < TAB_N) ? __uint_as_float(ws[TAB_WS + ki])
                                     : xla_lgammaf_pos(kf + 1.0f);
  float tv = fmaf(kf, rc.log_lam, rc.neg_lam) - lg;
  return sv <= tv;                                                  // accept2
}

__device__ __forceinline__ RejConst load_mrc(const uint32_t* __restrict__ ws) {
  RejConst rc;
  rc.lam       = __uint_as_float(ws[MRC_WS + 0]);
  rc.neg_lam   = __uint_as_float(ws[MRC_WS + 1]);
  rc.log_lam   = __uint_as_float(ws[MRC_WS + 2]);
  rc.aa        = __uint_as_float(ws[MRC_WS + 3]);
  rc.bb        = __uint_as_float(ws[MRC_WS + 4]);
  rc.inv_alpha = __uint_as_float(ws[MRC_WS + 5]);
  rc.v_r       = __uint_as_float(ws[MRC_WS + 6]);
  rc.two_a     = __uint_as_float(ws[MRC_WS + 7]);
  return rc;
}

// ---------------- prologue: chains + mrc + lgamma table ----------------------
__global__ void chain_init(uint32_t* __restrict__ ws, int build_table, int fast) {
  if (blockIdx.x == 0) {
    if (threadIdx.x != 0) return;
    ws[G_SLOT] = 1u;                       // G >= 1 always
    if (fast) { ws[CTR0_WS] = 0u; ws[CTR1_WS] = 0u; }
    uint32_t r0 = 0u, r1 = 42u;            // jax.random.key(42) -> (0,42)
    for (int j = 0; j < KN_MAX; ++j) {
      uint32_t s0, s1, n0, n1;
      tf2x32(r0, r1, 0u, 1u, s0, s1);
      tf2x32(r0, r1, 0u, 0u, n0, n1);
      ws[2 * j] = s0; ws[2 * j + 1] = s1;
      r0 = n0; r1 = n1;
    }
  } else if (blockIdx.x == 1) {
    if (threadIdx.x == 0) {
      uint32_t c0 = 0u, c1 = 42u;
      for (int j = 0; j < RJ_MAX; ++j) {
        uint32_t a0, a1, b0, b1, n0, n1;
        tf2x32(c0, c1, 0u, 1u, a0, a1);
        tf2x32(c0, c1, 0u, 2u, b0, b1);
        tf2x32(c0, c1, 0u, 0u, n0, n1);
        uint32_t base = KN_MAX * 2 + 4 * j;
        ws[base + 0] = a0; ws[base + 1] = a1; ws[base + 2] = b0; ws[base + 3] = b1;
        c0 = n0; c1 = n1;
      }
    } else if (threadIdx.x == 64) {
      RejConst m = make_rej(100000.0f);
      ws[MRC_WS + 0] = __float_as_uint(m.lam);
      ws[MRC_WS + 1] = __float_as_uint(m.neg_lam);
      ws[MRC_WS + 2] = __float_as_uint(m.log_lam);
      ws[MRC_WS + 3] = __float_as_uint(m.aa);
      ws[MRC_WS + 4] = __float_as_uint(m.bb);
      ws[MRC_WS + 5] = __float_as_uint(m.inv_alpha);
      ws[MRC_WS + 6] = __float_as_uint(m.v_r);
      ws[MRC_WS + 7] = __float_as_uint(m.two_a);
    }
  } else if (build_table) {
    int i = (blockIdx.x - 2) * 256 + threadIdx.x;   // 16 blocks x 256 = TAB_N
    if (i < TAB_N) {
      float kf = (float)(TAB_BASE + i);             // exact (< 2^24)
      ws[TAB_WS + i] = __float_as_uint(xla_lgammaf_pos(kf + 1.0f));
    }
  }
}

// ---------------- pass 0: accept1-fail bitmap, work-stealing waves -----------
// Per pixel: 100 t's, own v_r (both classes). Per-pixel register bitmap
// (bm0,bm1), one 16B store. Chunk = 64 pixels = 1 wave. Assignment order is
// replay-varying but output location is fixed by chunk id -> deterministic.
__global__ void __launch_bounds__(256)
pass0_all(const float* __restrict__ img, uint32_t* __restrict__ ws) {
  const int lane = threadIdx.x & 63;
  float mvr = __uint_as_float(ws[MRC_WS + 6]);
  uint4 ch0 = make_uint4(ws[KN_MAX * 2 + 0], ws[KN_MAX * 2 + 1],
                         ws[KN_MAX * 2 + 2], ws[KN_MAX * 2 + 3]);
  ulonglong2* bm = (ulonglong2*)(ws + BM_WS);

  while (true) {
    uint32_t c = 0;
    if (lane == 0) c = atomicAdd(ws + CTR0_WS, 1u);
    c = (uint32_t)__shfl((int)c, 0, 64);
    if (c >= (uint32_t)N_CHUNKS) break;

    uint32_t n = c * 64u + (uint32_t)lane;
    float uimg = img[n];
    bool isRej = (uimg != 0.0f) && !((1.0f / uimg) < 10.0f);
    float v_r = isRej ? vr_only(1.0f / uimg) : mvr;

    unsigned long long bm0 = 0ull, bm1 = 0ull;
    uint32_t p = n;
    for (int t = 0; t < T_WIN; t += 4) {
      uint32_t p0 = p, p1 = p + N_PIX, p2 = p + 2u * N_PIX, p3 = p + 3u * N_PIX;
      float u0 = bits_to_unit(unif_bits(ch0.x, ch0.y, p0)) - 0.5f;
      float v0 = bits_to_unit(unif_bits(ch0.z, ch0.w, p0));
      float u1 = bits_to_unit(unif_bits(ch0.x, ch0.y, p1)) - 0.5f;
      float v1 = bits_to_unit(unif_bits(ch0.z, ch0.w, p1));
      float u2 = bits_to_unit(unif_bits(ch0.x, ch0.y, p2)) - 0.5f;
      float v2 = bits_to_unit(unif_bits(ch0.z, ch0.w, p2));
      float u3 = bits_to_unit(unif_bits(ch0.x, ch0.y, p3)) - 0.5f;
      float v3 = bits_to_unit(unif_bits(ch0.z, ch0.w, p3));
      unsigned long long f0 = (!(((0.5f - fabsf(u0)) >= (float)0.07) && (v0 <= v_r))) ? 1ull : 0ull;
      unsigned long long f1 = (!(((0.5f - fabsf(u1)) >= (float)0.07) && (v1 <= v_r))) ? 1ull : 0ull;
      unsigned long long f2 = (!(((0.5f - fabsf(u2)) >= (float)0.07) && (v2 <= v_r))) ? 1ull : 0ull;
      unsigned long long f3 = (!(((0.5f - fabsf(u3)) >= (float)0.07) && (v3 <= v_r))) ? 1ull : 0ull;
      unsigned long long pack = f0 | (f1 << 1) | (f2 << 2) | (f3 << 3);
      if (t < 64) bm0 |= pack << t; else bm1 |= pack << (t - 64);
      p += 4u * N_PIX;
    }
    ulonglong2 v; v.x = bm0; v.y = bm1;
    bm[n] = v;
  }
}

// ---------------- pass 1: resolve fail bits per PIXEL, work-stealing ---------
__global__ void __launch_bounds__(256)
pass1(const float* __restrict__ img, uint32_t* __restrict__ ws,
      uint32_t* __restrict__ gmax) {
  __shared__ uint4 rj4[RJ_MAX];
  for (int i = threadIdx.x; i < RJ_MAX; i += 256) {
    uint32_t b = KN_MAX * 2 + 4 * i;
    rj4[i] = make_uint4(ws[b], ws[b + 1], ws[b + 2], ws[b + 3]);
  }
  __syncthreads();

  const int lane = threadIdx.x & 63;
  RejConst mrc = load_mrc(ws);
  const ulonglong2* bm = (const ulonglong2*)(ws + BM_WS);
  uint32_t mymax = 1;

  while (true) {
    uint32_t c = 0;
    if (lane == 0) c = atomicAdd(ws + CTR1_WS, 1u);
    c = (uint32_t)__shfl((int)c, 0, 64);
    if (c >= (uint32_t)N_CHUNKS) break;

    uint32_t n = c * 64u + (uint32_t)lane;
    ulonglong2 v = bm[n];
    if (v.x == 0ull && v.y == 0ull) continue;
    float uimg = img[n];
    bool isRej = (uimg != 0.0f) && !((1.0f / uimg) < 10.0f);
    RejConst rc = isRej ? make_rej(1.0f / uimg) : mrc;

    for (int half = 0; half < 2; ++half) {
      unsigned long long m = half ? v.y : v.x;
      uint32_t tbase = half ? 64u : 0u;
      while (m) {
        int b = __builtin_ctzll(m);
        m &= (m - 1);
        uint32_t p = (tbase + (uint32_t)b) * (uint32_t)N_PIX + n;
        uint32_t fa = RJ_MAX;
        for (int j = 0; j < RJ_MAX; ++j) {
          float kf;
          if (rej_step_tab_g(rc, rj4[j], p, ws, kf)) { fa = (uint32_t)(j + 1); break; }
        }
        if (fa > mymax) mymax = fa;
      }
    }
  }
  for (int s = 32; s > 0; s >>= 1) {
    uint32_t o = (uint32_t)__shfl_xor((int)mymax, s, 64);
    if (o > mymax) mymax = o;
  }
  if (lane == 0) atomicMax((unsigned int*)gmax, mymax);
}

// ---------------- fallback: full first-accept scan (r7 gmax) -----------------
__global__ void __launch_bounds__(512)
rej_gmax_full(const float* __restrict__ img, const uint32_t* __restrict__ ws,
              uint32_t* __restrict__ gmax, int use_table) {
  __shared__ uint4 rj4[RJ_MAX];
  __shared__ int waveRej[8];
  __shared__ unsigned short order[512];
  __shared__ uint32_t red[512];

  const int tid = threadIdx.x;
  for (int i = tid; i < RJ_MAX; i += 512) {
    uint32_t b = KN_MAX * 2 + 4 * i;
    rj4[i] = make_uint4(ws[b], ws[b + 1], ws[b + 2], ws[b + 3]);
  }

  int n0 = blockIdx.x * 512 + tid;
  float uimg0 = img[n0];
  bool isRej = (uimg0 != 0.0f) && !((1.0f / uimg0) < 10.0f);
  int lane = tid & 63, w = tid >> 6;
  unsigned long long bal = __ballot(isRej ? 1 : 0);
  int within = (int)__popcll(bal & ((1ull << lane) - 1ull));
  if (lane == 0) waveRej[w] = (int)__popcll(bal);
  __syncthreads();
  int rejBefore = 0, totalRej = 0;
  for (int i = 0; i < 8; ++i) { int c = waveRej[i]; totalRej += c; if (i < w) rejBefore += c; }
  int nMasked = 512 - totalRej;
  int slot = isRej ? (nMasked + rejBefore + within)
                   : (64 * w - rejBefore) + (lane - within);
  order[slot] = (unsigned short)tid;
  __syncthreads();

  int n = blockIdx.x * 512 + (int)order[tid];
  bool myRej = (tid >= nMasked);
  RejConst rc = make_rej(myRej ? (1.0f / img[n]) : 100000.0f);

  uint32_t mymax = 1;
  {
    uint32_t p = (uint32_t)n;
    int t = 0, j = 0;
    while (t < T_WIN) {
      float kf;
      bool acc;
      if (use_table) acc = rej_step_tab_g(rc, rj4[j], p, ws, kf);
      else           acc = rej_step4(rc, rj4[j], p, kf);
      if (acc) {
        uint32_t fa = (uint32_t)(j + 1);
        if (fa > mymax) mymax = fa;
        ++t; p += N_PIX; j = 0;
      } else if (++j >= RJ_MAX) {
        mymax = RJ_MAX;
        ++t; p += N_PIX; j = 0;
      }
    }
  }
  red[tid] = mymax;
  __syncthreads();
  for (int s2 = 256; s2 > 0; s2 >>= 1) {
    if (tid < s2) {
      uint32_t o = red[tid + s2];
      if (o > red[tid]) red[tid] = o;
    }
    __syncthreads();
  }
  if (tid == 0) atomicMax((unsigned int*)gmax, red[0]);
}

// ---------------- pass 2: one thread per pixel, compacted + flattened --------
__global__ void __launch_bounds__(512)
spike_main(const float* __restrict__ img, int* __restrict__ out,
           const uint32_t* __restrict__ chains) {
  __shared__ uint2 kn2[KN_MAX];
  __shared__ uint4 rj4[RJ_MAX];
  __shared__ int waveRej[8];
  __shared__ unsigned short order[512];
  __shared__ int shG;
  __shared__ ulonglong2 bmsh[512];

  const int tid = threadIdx.x;
  for (int i = tid; i < KN_MAX; i += 512)
    kn2[i] = make_uint2(chains[2 * i], chains[2 * i + 1]);
  for (int i = tid; i < RJ_MAX; i += 512) {
    uint32_t b = KN_MAX * 2 + 4 * i;
    rj4[i] = make_uint4(chains[b], chains[b + 1], chains[b + 2], chains[b + 3]);
  }
  if (tid == 0) {
    int g = (int)chains[G_SLOT];
    if (g < 1) g = 1;
    if (g > RJ_MAX) g = RJ_MAX;   // bounds-safety for rj4 indexing
    shG = g;
  }

  int n0 = blockIdx.x * 512 + tid;
  float uimg0 = img[n0];
  bool isRej = (uimg0 != 0.0f) && !((1.0f / uimg0) < 10.0f);
  int lane = tid & 63, w = tid >> 6;
  unsigned long long bal = __ballot(isRej ? 1 : 0);
  int within = (int)__popcll(bal & ((1ull << lane) - 1ull));
  if (lane == 0) waveRej[w] = (int)__popcll(bal);
  __syncthreads();
  int rejBefore = 0, totalRej = 0;
  for (int i = 0; i < 8; ++i) { int c = waveRej[i]; totalRej += c; if (i < w) rejBefore += c; }
  int nMasked = 512 - totalRej;
  int slot = isRej ? (nMasked + rejBefore + within)
                   : (64 * w - rejBefore) + (lane - within);
  order[slot] = (unsigned short)tid;
  __syncthreads();

  const int G = shG;
  int nl = (int)order[tid];
  int n = blockIdx.x * 512 + nl;
  bool myRej = (tid >= nMasked);
  float uimg = img[n];
  unsigned long long bm0 = 0ull, bm1 = 0ull;  // spike bitmap: bit (s-1), s in [1,100]

  if (myRej) {
    // Rejection: last accept in [0,G) == first accept scanning DOWN
    RejConst rc = make_rej(1.0f / uimg);
    uint32_t p = (uint32_t)n;
    int s = 0, j = G - 1, t = 0;
    while (t < T_WIN) {
      float kf;
      bool acc = rej_step4(rc, rj4[j], p, kf);
      if (acc) {
        int iv = (kf >= 102.0f) ? 102 : (int)kf;  // values >100 all dead
        if (iv == 0) iv = 1;
        s += iv;
        if (s > T_WIN) break;
        if (s <= 64) bm0 |= 1ull << (s - 1); else bm1 |= 1ull << (s - 65);
        ++t; p += N_PIX; j = G - 1;
      } else if (--j < 0) {
        break;  // impossible: G covers every position's first accept
      }
    }
  } else if (uimg != 0.0f) {
    // Knuth, flattened: one draw per step, per-lane (t,j,k,lp,s)
    float lam = 1.0f / uimg;
    float neg_lam = -lam;
    uint32_t p = (uint32_t)n;
    int s = 0, k = 0, j = 0;
    float lp = 0.0f;
    while (true) {
      uint2 sk = kn2[j];
      float u = bits_to_unit(unif_bits(sk.x, sk.y, p));
      ++k; ++j;
      lp = lp + xla_logf(u);
      if (lp <= neg_lam || j >= KN_MAX) {   // this t resolved
        int iv = k - 1;
        if (iv == 0) iv = 1;                // nz & interval==0 -> 1
        s += iv;
        if (s > T_WIN) break;               // integer cumsum <=100 exact
        if (s <= 64) bm0 |= 1ull << (s - 1); else bm1 |= 1ull << (s - 65);
        p += N_PIX; j = 0; k = 0; lp = 0.0f;
        if (p >= (uint32_t)T_WIN * (uint32_t)N_PIX) break;
      }
    }
  }

  // Stage bitmaps in LDS, write columns in ORIGINAL pixel order (coalesced).
  ulonglong2 bm; bm.x = bm0; bm.y = bm1;
  bmsh[nl] = bm;
  __syncthreads();
  ulonglong2 b2 = bmsh[tid];
  size_t base = (size_t)(blockIdx.x * 512 + tid);
  for (int t = 0; t < 64; ++t)
    out[base + (size_t)t * N_PIX] = (int)((b2.x >> t) & 1ull);
  for (int t = 64; t < T_WIN; ++t)
    out[base + (size_t)t * N_PIX] = (int)((b2.y >> (t - 64)) & 1ull);
}

extern "C" void kernel_launch(void* const* d_in, const int* in_sizes, int n_in,
                              void* d_out, int out_size, void* d_ws, size_t ws_size,
                              hipStream_t stream) {
  const float* img = (const float*)d_in[0];
  int* out = (int*)d_out;
  uint32_t* ws = (uint32_t*)d_ws;
  int use_table = (ws_size >= WS_TAB_NEEDED) ? 1 : 0;
  int use_fast  = (use_table && ws_size >= WS_FAST_NEEDED) ? 1 : 0;

  hipLaunchKernelGGL(chain_init, dim3(2 + TAB_N / 256), dim3(256), 0, stream,
                     ws, use_table, use_fast);
  if (use_fast) {
    hipLaunchKernelGGL(pass0_all, dim3(2048), dim3(256), 0, stream, img, ws);
    hipLaunchKernelGGL(pass1, dim3(2048), dim3(256), 0, stream,
                       img, ws, ws + G_SLOT);
  } else {
    hipLaunchKernelGGL(rej_gmax_full, dim3(N_PIX / 512), dim3(512), 0, stream,
                       img, ws, ws + G_SLOT, use_table);
  }
  hipLaunchKernelGGL(spike_main, dim3(N_PIX / 512), dim3(512), 0, stream,
                     img, out, ws);
}

// Round 14
// 1256.675 us; speedup vs baseline: 1.8530x; 1.8530x over previous
//
#include <hip/hip_runtime.h>
#include <math.h>
#include <stdint.h>

// Keep compiler contraction OFF globally: the ONLY fusions are my explicit
// fmaf() calls, which model LLVM's contract-FMF fusion on the XLA CPU host.
#pragma clang fp contract(off)

#define N_PIX 802816          // 16*1*224*224 = 512*1568
#define T_WIN 100
#define KN_MAX 96             // Knuth subkey chain length
#define RJ_MAX 48             // rejection subkey chain length (G ~ 10)
#define N_CHUNK 1568          // 512-pixel chunks

#define G_SLOT 384            // = KN_MAX*2 + RJ_MAX*4
#define CTR0_WS 385           // gmax work-steal counter
#define CTR1_WS 386           // spike work-steal counter
#define TAB_WS  400
#define TAB_BASE 98000
#define TAB_N    4096
#define WS_TAB_NEEDED ((size_t)(TAB_WS + TAB_N) * 4)   // ~18 KB

// ---------------- threefry2x32 (JAX rotation/injection schedule) -------------
__device__ __forceinline__ void tf2x32(uint32_t k0, uint32_t k1,
                                       uint32_t x0, uint32_t x1,
                                       uint32_t &o0, uint32_t &o1) {
  uint32_t ks2 = k0 ^ k1 ^ 0x1BD11BDAu;
  x0 += k0; x1 += k1;
#define TF_R(r) { x0 += x1; x1 = (x1 << (r)) | (x1 >> (32 - (r))); x1 ^= x0; }
  TF_R(13) TF_R(15) TF_R(26) TF_R(6)
  x0 += k1;  x1 += ks2 + 1u;
  TF_R(17) TF_R(29) TF_R(16) TF_R(24)
  x0 += ks2; x1 += k0 + 2u;
  TF_R(13) TF_R(15) TF_R(26) TF_R(6)
  x0 += k0;  x1 += k1 + 3u;
  TF_R(17) TF_R(29) TF_R(16) TF_R(24)
  x0 += k1;  x1 += ks2 + 4u;
  TF_R(13) TF_R(15) TF_R(26) TF_R(6)
  x0 += ks2; x1 += k0 + 5u;
#undef TF_R
  o0 = x0; o1 = x1;
}

__device__ __forceinline__ uint32_t unif_bits(uint32_t s0, uint32_t s1, uint32_t p) {
  uint32_t a, b;
  tf2x32(s0, s1, 0u, p, a, b);
  return a ^ b;
}

__device__ __forceinline__ float bits_to_unit(uint32_t bits) {
  return __uint_as_float(0x3f800000u | (bits >> 9)) - 1.0f;
}

// ---------------- XLA CPU f32 log (verified bit-exact in round 5) ------------
__device__ __forceinline__ float xla_logf(float xin) {
#pragma clang fp contract(off)
  if (xin == 0.0f) return __uint_as_float(0xff800000u);           // -inf
  if (!(xin > 0.0f)) return __uint_as_float(0x7fc00000u);         // nan
  float x = fmaxf(xin, __uint_as_float(0x00800000u));             // flush denorm
  uint32_t ib = __float_as_uint(x);
  float e = (float)((int)(ib >> 23) - 126);
  ib = (ib & 0x007fffffu) | 0x3f000000u;                          // [0.5,1)
  x = __uint_as_float(ib);
  float tmp = 0.0f, eadj = 0.0f;
  if (x < (float)0.707106781186547524) { tmp = x; eadj = 1.0f; }
  x = x - 1.0f;
  e = e - eadj;
  x = x + tmp;
  float x2 = x * x;
  float x3 = x2 * x;
  float y  = fmaf((float)7.0376836292e-2,  x, (float)-1.1514610310e-1);
  float y1 = fmaf((float)-1.2420140846e-1, x, (float)1.4249322787e-1);
  float y2 = fmaf((float)2.0000714765e-1,  x, (float)-2.4999993993e-1);
  y  = fmaf(y,  x, (float)1.1676998740e-1);
  y1 = fmaf(y1, x, (float)-1.6668057665e-1);
  y2 = fmaf(y2, x, (float)3.3333331174e-1);
  y  = fmaf(y, x3, y1);
  y  = fmaf(y, x3, y2);
  float eq1 = e * (float)-2.12194440e-4;   // standalone mul
  y = fmaf(y, x3, eq1);                    // fadd(mul,mul): operand-0 fuses
  x = fmaf(-x2, 0.5f, x);                  // fsub(x, mul) -> fnmadd
  x = x + y;                               // add of two fma results
  x = fmaf(e, (float)0.693359375, x);      // fadd(x, mul) -> fma
  return x;
}

__device__ __forceinline__ float xla_log1pf(float w) {
#pragma clang fp contract(off)
  if (fabsf(w) < (float)1e-4) return fmaf(-0.5f, w, 1.0f) * w;
  return xla_logf(w + 1.0f);
}

__device__ __forceinline__ float xla_lgammaf_pos(float x) {
#pragma clang fp contract(off)
  const float kBase = (float)0.99999999999980993227684700473478;
  const float c0 = (float)676.520368121885098567009190444019;
  const float c1 = (float)-1259.13921672240287047156078755283;
  const float c2 = (float)771.3234287776530788486528258894;
  const float c3 = (float)-176.61502916214059906584551354;
  const float c4 = (float)12.507343278686904814458936853;
  const float c5 = (float)-0.13857109526572011689554707;
  const float c6 = (float)9.984369578019570859563e-6;
  const float c7 = (float)1.50563273514931155834e-7;
  const float kLogSqrtTwoPi = (float)0.91893853320467274178032973640562;
  const float kGPlusHalf = 7.5f;
  const float kLogGPlusHalf = (float)2.0149030205422647065; // log(7.5)
  float z = x - 1.0f;
  float sum = kBase;
  sum = sum + c0 / ((z + 0.0f) + 1.0f);
  sum = sum + c1 / ((z + 1.0f) + 1.0f);
  sum = sum + c2 / ((z + 2.0f) + 1.0f);
  sum = sum + c3 / ((z + 3.0f) + 1.0f);
  sum = sum + c4 / ((z + 4.0f) + 1.0f);
  sum = sum + c5 / ((z + 5.0f) + 1.0f);
  sum = sum + c6 / ((z + 6.0f) + 1.0f);
  sum = sum + c7 / ((z + 7.0f) + 1.0f);
  float t = kGPlusHalf + z;
  float log_t = kLogGPlusHalf + xla_log1pf(z / kGPlusHalf);
  float log_y = fmaf((z + 0.5f) - t / log_t, log_t, kLogSqrtTwoPi) + xla_logf(sum);
  return log_y;
}

// ---------------- rejection sampler shared pieces ----------------------------
struct RejConst {
  float lam, neg_lam, log_lam, aa, bb, inv_alpha, v_r, two_a;
};

__device__ __forceinline__ RejConst make_rej(float lam) {
  RejConst rc;
  rc.lam = lam;
  rc.neg_lam = -lam;
  rc.log_lam = xla_logf(lam);
  float sq = (float)sqrt((double)lam);                  // CR f32 sqrt
  rc.bb = fmaf(2.53f, sq, (float)0.931);
  rc.aa = fmaf((float)0.02483, rc.bb, (float)-0.059);
  rc.inv_alpha = (float)1.1239 + (float)1.1328 / (rc.bb - (float)3.4);
  rc.v_r = (float)0.9277 - (float)3.6224 / (rc.bb - 2.0f);
  rc.two_a = 2.0f * rc.aa;
  return rc;
}

// One rejection iteration (full lgamma) -- byte-identical to rounds 5-13.
__device__ __forceinline__ bool rej_step4(const RejConst& rc, uint4 ch,
                                          uint32_t p, float& kf_out) {
  float u = bits_to_unit(unif_bits(ch.x, ch.y, p)) - 0.5f;
  float v = bits_to_unit(unif_bits(ch.z, ch.w, p));
  float u_sh = 0.5f - fabsf(u);
  float kf = floorf(fmaf(rc.two_a / u_sh + rc.bb, u, rc.lam) + (float)0.43);
  kf_out = kf;
  if ((u_sh >= (float)0.07) && (v <= rc.v_r)) return true;          // accept1
  if ((kf < 0.0f) || ((u_sh < (float)0.013) && (v > u_sh))) return false; // reject
  float sv = xla_logf((v * rc.inv_alpha) / ((rc.aa / (u_sh * u_sh)) + rc.bb));
  float tv = fmaf(kf, rc.log_lam, rc.neg_lam) - xla_lgammaf_pos(kf + 1.0f);
  return sv <= tv;                                                  // accept2
}

// LDS-table-assisted variant (table = xla_lgammaf_pos(kf+1), pure fn of kf;
// out-of-range falls back to the full function -> identical bits).
__device__ __forceinline__ bool rej_step_lds(const RejConst& rc, uint4 ch,
                                             uint32_t p, const float* lgtab,
                                             float& kf_out) {
  float u = bits_to_unit(unif_bits(ch.x, ch.y, p)) - 0.5f;
  float v = bits_to_unit(unif_bits(ch.z, ch.w, p));
  float u_sh = 0.5f - fabsf(u);
  float kf = floorf(fmaf(rc.two_a / u_sh + rc.bb, u, rc.lam) + (float)0.43);
  kf_out = kf;
  if ((u_sh >= (float)0.07) && (v <= rc.v_r)) return true;          // accept1
  if ((kf < 0.0f) || ((u_sh < (float)0.013) && (v > u_sh))) return false; // reject
  float sv = xla_logf((v * rc.inv_alpha) / ((rc.aa / (u_sh * u_sh)) + rc.bb));
  int ki = (int)kf - TAB_BASE;
  float lg = (ki >= 0 && ki < TAB_N) ? lgtab[ki] : xla_lgammaf_pos(kf + 1.0f);
  float tv = fmaf(kf, rc.log_lam, rc.neg_lam) - lg;
  return sv <= tv;                                                  // accept2
}

// ---------------- prologue: chains + counters + lgamma table -----------------
__global__ void chain_init(uint32_t* __restrict__ ws, int build_table) {
  if (blockIdx.x == 0) {
    if (threadIdx.x != 0) return;
    ws[G_SLOT] = 1u;                       // G >= 1 always
    ws[CTR0_WS] = 0u; ws[CTR1_WS] = 0u;
    uint32_t r0 = 0u, r1 = 42u;            // jax.random.key(42) -> (0,42)
    for (int j = 0; j < KN_MAX; ++j) {
      uint32_t s0, s1, n0, n1;
      tf2x32(r0, r1, 0u, 1u, s0, s1);
      tf2x32(r0, r1, 0u, 0u, n0, n1);
      ws[2 * j] = s0; ws[2 * j + 1] = s1;
      r0 = n0; r1 = n1;
    }
  } else if (blockIdx.x == 1) {
    if (threadIdx.x != 0) return;
    uint32_t c0 = 0u, c1 = 42u;
    for (int j = 0; j < RJ_MAX; ++j) {
      uint32_t a0, a1, b0, b1, n0, n1;
      tf2x32(c0, c1, 0u, 1u, a0, a1);
      tf2x32(c0, c1, 0u, 2u, b0, b1);
      tf2x32(c0, c1, 0u, 0u, n0, n1);
      uint32_t base = KN_MAX * 2 + 4 * j;
      ws[base + 0] = a0; ws[base + 1] = a1; ws[base + 2] = b0; ws[base + 3] = b1;
      c0 = n0; c1 = n1;
    }
  } else if (build_table) {
    int i = (blockIdx.x - 2) * 256 + threadIdx.x;   // 16 blocks x 256 = TAB_N
    if (i < TAB_N) {
      float kf = (float)(TAB_BASE + i);             // exact (< 2^24)
      ws[TAB_WS + i] = __float_as_uint(xla_lgammaf_pos(kf + 1.0f));
    }
  }
}

// ---------------- gmax: r7 body, persistent work-stealing blocks -------------
// Grid 1024 x 512 = exactly 4 blocks/CU resident. Chunk = 512 pixels; chunk id
// fixes all reads; gmax is an order-independent max -> replay-deterministic.
__global__ void __launch_bounds__(512)
gmax_ws(const float* __restrict__ img, uint32_t* __restrict__ ws,
        uint32_t* __restrict__ gmax) {
  __shared__ uint4 rj4[RJ_MAX];
  __shared__ float lgtab[TAB_N];
  __shared__ int waveRej[8];
  __shared__ unsigned short order[512];
  __shared__ uint32_t red[512];
  __shared__ uint32_t curC;

  const int tid = threadIdx.x;
  for (int i = tid; i < RJ_MAX; i += 512) {
    uint32_t b = KN_MAX * 2 + 4 * i;
    rj4[i] = make_uint4(ws[b], ws[b + 1], ws[b + 2], ws[b + 3]);
  }
  for (int i = tid; i < TAB_N; i += 512)
    lgtab[i] = __uint_as_float(ws[TAB_WS + i]);

  uint32_t mymax = 1;
  while (true) {
    __syncthreads();                                   // LDS reuse guard
    if (tid == 0) curC = atomicAdd(ws + CTR0_WS, 1u);
    __syncthreads();
    uint32_t c = curC;
    if (c >= (uint32_t)N_CHUNK) break;                 // uniform exit

    // ---- r7 body: classify + deterministic compaction ----
    int n0 = (int)c * 512 + tid;
    float uimg0 = img[n0];
    bool isRej = (uimg0 != 0.0f) && !((1.0f / uimg0) < 10.0f);
    int lane = tid & 63, w = tid >> 6;
    unsigned long long bal = __ballot(isRej ? 1 : 0);
    int within = (int)__popcll(bal & ((1ull << lane) - 1ull));
    if (lane == 0) waveRej[w] = (int)__popcll(bal);
    __syncthreads();
    int rejBefore = 0, totalRej = 0;
    for (int i = 0; i < 8; ++i) { int cc = waveRej[i]; totalRej += cc; if (i < w) rejBefore += cc; }
    int nMasked = 512 - totalRej;
    int slot = isRej ? (nMasked + rejBefore + within)
                     : (64 * w - rejBefore) + (lane - within);
    order[slot] = (unsigned short)tid;
    __syncthreads();

    int n = (int)c * 512 + (int)order[tid];
    bool myRej = (tid >= nMasked);
    RejConst rc = make_rej(myRej ? (1.0f / img[n]) : 100000.0f);

    // ---- flattened first-accept automaton (r7) ----
    uint32_t p = (uint32_t)n;
    int t = 0, j = 0;
    while (t < T_WIN) {
      float kf;
      bool acc = rej_step_lds(rc, rj4[j], p, lgtab, kf);
      if (acc) {
        uint32_t fa = (uint32_t)(j + 1);
        if (fa > mymax) mymax = fa;
        ++t; p += N_PIX; j = 0;
      } else if (++j >= RJ_MAX) {       // safety cap (never hit)
        mymax = RJ_MAX;
        ++t; p += N_PIX; j = 0;
      }
    }
  }

  red[tid] = mymax;
  __syncthreads();
  for (int s2 = 256; s2 > 0; s2 >>= 1) {
    if (tid < s2) {
      uint32_t o = red[tid + s2];
      if (o > red[tid]) red[tid] = o;
    }
    __syncthreads();
  }
  if (tid == 0) atomicMax((unsigned int*)gmax, red[0]);
}

// ---------------- fallback gmax: fixed grid, no table (never taken) ----------
__global__ void __launch_bounds__(512)
rej_gmax_full(const float* __restrict__ img, const uint32_t* __restrict__ ws,
              uint32_t* __restrict__ gmax) {
  __shared__ uint4 rj4[RJ_MAX];
  __shared__ uint32_t red[512];
  const int tid = threadIdx.x;
  for (int i = tid; i < RJ_MAX; i += 512) {
    uint32_t b = KN_MAX * 2 + 4 * i;
    rj4[i] = make_uint4(ws[b], ws[b + 1], ws[b + 2], ws[b + 3]);
  }
  __syncthreads();
  int n = blockIdx.x * 512 + tid;
  float uimg = img[n];
  bool isRej = (uimg != 0.0f) && !((1.0f / uimg) < 10.0f);
  RejConst rc = make_rej(isRej ? (1.0f / uimg) : 100000.0f);
  uint32_t mymax = 1;
  uint32_t p = (uint32_t)n;
  int t = 0, j = 0;
  while (t < T_WIN) {
    float kf;
    bool acc = rej_step4(rc, rj4[j], p, kf);
    if (acc) {
      uint32_t fa = (uint32_t)(j + 1);
      if (fa > mymax) mymax = fa;
      ++t; p += N_PIX; j = 0;
    } else if (++j >= RJ_MAX) {
      mymax = RJ_MAX;
      ++t; p += N_PIX; j = 0;
    }
  }
  red[tid] = mymax;
  __syncthreads();
  for (int s2 = 256; s2 > 0; s2 >>= 1) {
    if (tid < s2) {
      uint32_t o = red[tid + s2];
      if (o > red[tid]) red[tid] = o;
    }
    __syncthreads();
  }
  if (tid == 0) atomicMax((unsigned int*)gmax, red[0]);
}

// ---------------- spike: r7 body, persistent work-stealing blocks ------------
__global__ void __launch_bounds__(512)
spike_ws(const float* __restrict__ img, int* __restrict__ out,
         const uint32_t* __restrict__ chains, uint32_t* __restrict__ wsctr) {
  __shared__ uint2 kn2[KN_MAX];
  __shared__ uint4 rj4[RJ_MAX];
  __shared__ int waveRej[8];
  __shared__ unsigned short order[512];
  __shared__ int shG;
  __shared__ ulonglong2 bmsh[512];
  __shared__ uint32_t curC;

  const int tid = threadIdx.x;
  for (int i = tid; i < KN_MAX; i += 512)
    kn2[i] = make_uint2(chains[2 * i], chains[2 * i + 1]);
  for (int i = tid; i < RJ_MAX; i += 512) {
    uint32_t b = KN_MAX * 2 + 4 * i;
    rj4[i] = make_uint4(chains[b], chains[b + 1], chains[b + 2], chains[b + 3]);
  }
  if (tid == 0) {
    int g = (int)chains[G_SLOT];
    if (g < 1) g = 1;
    if (g > RJ_MAX) g = RJ_MAX;   // bounds-safety for rj4 indexing
    shG = g;
  }

  while (true) {
    __syncthreads();                                   // LDS reuse guard
    if (tid == 0) curC = atomicAdd(wsctr, 1u);
    __syncthreads();
    uint32_t c = curC;
    if (c >= (uint32_t)N_CHUNK) break;                 // uniform exit

    // ---- classify + deterministic compaction (r7) ----
    int n0 = (int)c * 512 + tid;
    float uimg0 = img[n0];
    bool isRej = (uimg0 != 0.0f) && !((1.0f / uimg0) < 10.0f);
    int lane = tid & 63, w = tid >> 6;
    unsigned long long bal = __ballot(isRej ? 1 : 0);
    int within = (int)__popcll(bal & ((1ull << lane) - 1ull));
    if (lane == 0) waveRej[w] = (int)__popcll(bal);
    __syncthreads();
    int rejBefore = 0, totalRej = 0;
    for (int i = 0; i < 8; ++i) { int cc = waveRej[i]; totalRej += cc; if (i < w) rejBefore += cc; }
    int nMasked = 512 - totalRej;
    int slot = isRej ? (nMasked + rejBefore + within)
                     : (64 * w - rejBefore) + (lane - within);
    order[slot] = (unsigned short)tid;
    __syncthreads();

    const int G = shG;
    int nl = (int)order[tid];
    int n = (int)c * 512 + nl;
    bool myRej = (tid >= nMasked);
    float uimg = img[n];
    unsigned long long bm0 = 0ull, bm1 = 0ull;  // spike bits: (s-1), s in [1,100]

    if (myRej) {
      // Rejection: last accept in [0,G) == first accept scanning DOWN
      RejConst rc = make_rej(1.0f / uimg);
      uint32_t p = (uint32_t)n;
      int s = 0, j = G - 1, t = 0;
      while (t < T_WIN) {
        float kf;
        bool acc = rej_step4(rc, rj4[j], p, kf);
        if (acc) {
          int iv = (kf >= 102.0f) ? 102 : (int)kf;  // values >100 all dead
          if (iv == 0) iv = 1;
          s += iv;
          if (s > T_WIN) break;
          if (s <= 64) bm0 |= 1ull << (s - 1); else bm1 |= 1ull << (s - 65);
          ++t; p += N_PIX; j = G - 1;
        } else if (--j < 0) {
          break;  // impossible: G covers every position's first accept
        }
      }
    } else if (uimg != 0.0f) {
      // Knuth, flattened: one draw per step, per-lane (t,j,k,lp,s)
      float lam = 1.0f / uimg;
      float neg_lam = -lam;
      uint32_t p = (uint32_t)n;
      int s = 0, k = 0, j = 0;
      float lp = 0.0f;
      while (true) {
        uint2 sk = kn2[j];
        float u = bits_to_unit(unif_bits(sk.x, sk.y, p));
        ++k; ++j;
        lp = lp + xla_logf(u);
        if (lp <= neg_lam || j >= KN_MAX) {   // this t resolved
          int iv = k - 1;
          if (iv == 0) iv = 1;                // nz & interval==0 -> 1
          s += iv;
          if (s > T_WIN) break;               // integer cumsum <=100 exact
          if (s <= 64) bm0 |= 1ull << (s - 1); else bm1 |= 1ull << (s - 65);
          p += N_PIX; j = 0; k = 0; lp = 0.0f;
          if (p >= (uint32_t)T_WIN * (uint32_t)N_PIX) break;
        }
      }
    }

    // Stage bitmaps in LDS, write columns in ORIGINAL pixel order (coalesced).
    ulonglong2 bm; bm.x = bm0; bm.y = bm1;
    bmsh[nl] = bm;
    __syncthreads();
    ulonglong2 b2 = bmsh[tid];
    size_t base = (size_t)((size_t)c * 512 + (size_t)tid);
    for (int t = 0; t < 64; ++t)
      out[base + (size_t)t * N_PIX] = (int)((b2.x >> t) & 1ull);
    for (int t = 64; t < T_WIN; ++t)
      out[base + (size_t)t * N_PIX] = (int)((b2.y >> (t - 64)) & 1ull);
  }
}

extern "C" void kernel_launch(void* const* d_in, const int* in_sizes, int n_in,
                              void* d_out, int out_size, void* d_ws, size_t ws_size,
                              hipStream_t stream) {
  const float* img = (const float*)d_in[0];
  int* out = (int*)d_out;
  uint32_t* ws = (uint32_t*)d_ws;
  int use_table = (ws_size >= WS_TAB_NEEDED) ? 1 : 0;

  hipLaunchKernelGGL(chain_init, dim3(2 + TAB_N / 256), dim3(256), 0, stream,
                     ws, use_table);
  if (use_table) {
    hipLaunchKernelGGL(gmax_ws, dim3(1024), dim3(512), 0, stream,
                       img, ws, ws + G_SLOT);
  } else {
    hipLaunchKernelGGL(rej_gmax_full, dim3(N_PIX / 512), dim3(512), 0, stream,
                       img, ws, ws + G_SLOT);
  }
  hipLaunchKernelGGL(spike_ws, dim3(1024), dim3(512), 0, stream,
                     img, out, ws, ws + CTR1_WS);
}